// Round 5
// baseline (66.258 us; speedup 1.0000x reference)
//
#include <hip/hip_runtime.h>
#include <math.h>

#define NUM_CLASSES 80
#define M_GT 128
#define IOU_THR 0.3f

// ws layout: [0,24): double acc[3] = {box_l, cls_l, npos}
__global__ void yolo_init_acc(double* acc) {
    if (threadIdx.x < 3) acc[threadIdx.x] = 0.0;
}

__device__ __forceinline__ float focal_neg(float x) {
    // (1-ALPHA)=0.75, t=0 term: 0.75 * p^2 * (max(x,0)+log1p(exp(-|x|)))
    float ax = fabsf(x);
    float e  = __expf(-ax);
    float s  = 1.f + e;
    float r  = __builtin_amdgcn_rcpf(s);
    float l1p = __logf(s);
    float ce0 = fmaxf(x, 0.f) + l1p;
    float pr  = (x >= 0.f) ? r : e * r;      // sigmoid(x)
    return 0.75f * pr * pr * ce0;
}

__device__ __forceinline__ float focal_target_corr(float x) {
    // replace t=0 term with t=1 term for the target class
    float ax = fabsf(x);
    float e  = __expf(-ax);
    float s  = 1.f + e;
    float r  = __builtin_amdgcn_rcpf(s);
    float l1p = __logf(s);
    float ce0 = fmaxf(x, 0.f) + l1p;
    float pr  = (x >= 0.f) ? r : e * r;
    float om  = 1.f - pr;
    return 0.25f * om * om * (ce0 - x) - 0.75f * pr * pr * ce0;
}

// one GIoU evaluation against LDS-resident GT box; only VALU + the caller's ds_read
__device__ __forceinline__ float giou_pair(const float4& p, float pw, float ph, float a1,
                                           const float4& g) {
    float wx = g.z - g.x, wy = g.w - g.y;
    float a2 = wx * wy;
    float dx = fminf(p.z, g.z) - fmaxf(p.x, g.x);
    float dy = fminf(p.w, g.w) - fmaxf(p.y, g.y);
    float w  = fmaxf(dx, 0.f), h = fmaxf(dy, 0.f);
    float inter = w * h;
    float uni   = (a1 + a2) - inter;
    float ex = (pw + wx) - dx;          // == max(z) - min(x)  (identity, >=0 for valid boxes)
    float ey = (ph + wy) - dy;
    float ae = ex * ey;
    return fmaf(uni, __builtin_amdgcn_rcpf(ae),
                fmaf(inter, __builtin_amdgcn_rcpf(uni), -1.f));
}

__global__ __launch_bounds__(256) void yolo_fused_kernel(
    const float* __restrict__ box_preds,   // [B,N,4]
    const float* __restrict__ cls_preds,   // [B,N,C]
    const float* __restrict__ gt_boxes,    // [B,M,4]
    const int*   __restrict__ gt_labels,   // [B,M]
    double* __restrict__ acc,              // {box_l, cls_l, npos}
    int N)
{
    const int b   = blockIdx.y;
    const int tid = threadIdx.x;
    const int n   = blockIdx.x * 256 + tid;

    __shared__ float4   gta[M_GT];
    __shared__ int      s_cnt;
    __shared__ unsigned plist[256];
    __shared__ float    redb[4], redc[4];

    if (tid == 0) s_cnt = 0;
    if (tid < M_GT)
        gta[tid] = reinterpret_cast<const float4*>(gt_boxes + (size_t)b * M_GT * 4)[tid];
    __syncthreads();

    float4 p = reinterpret_cast<const float4*>(box_preds + (size_t)b * N * 4)[n];
    const float pw = p.z - p.x;
    const float ph = p.w - p.y;
    const float a1 = pw * ph;

    // two independent argmax chains (m and m+64) -> 2x ILP, merged below
    float best0 = -1e30f, best1 = -1e30f;
    int   bi0 = 0, bi1 = 64;

    #pragma unroll 4
    for (int m = 0; m < 64; ++m) {
        {
            float4 g = gta[m];
            float gi = giou_pair(p, pw, ph, a1, g);
            if (gi > best0) { best0 = gi; bi0 = m; }        // strict > keeps first idx
        }
        {
            float4 g = gta[m + 64];
            float gi = giou_pair(p, pw, ph, a1, g);
            if (gi > best1) { best1 = gi; bi1 = m + 64; }
        }
    }
    // merge: chain0 indices < chain1 indices, so strict > gives first-wins tie-break
    float best = best0;
    int   bidx = bi0;
    if (best1 > best0) { best = best1; bidx = bi1; }

    const int lane = tid & 63;
    const int wave = tid >> 6;

    bool  pos   = (n < N) && (best > IOU_THR);
    float box_l = pos ? (1.f - best) : 0.f;   // elementwise giou(pred, matched) == best

    // block-level compaction of positives into LDS
    {
        unsigned long long mk = __ballot(pos);
        int cw = __popcll(mk);
        if (cw > 0) {
            int leader = __ffsll(mk) - 1;
            int base = 0;
            if (lane == leader) base = atomicAdd(&s_cnt, cw);
            base = __shfl(base, leader);
            if (pos) {
                int pre = __popcll(mk & ((1ull << lane) - 1ull));
                unsigned lbl = (unsigned)gt_labels[b * M_GT + bidx];
                plist[base + pre] = (lbl << 18) | (unsigned)(b * N + n);
            }
        }
    }
    __syncthreads();

    // focal over the block's compacted positives (~17 avg)
    const int cnt = s_cnt;
    float cls_l = 0.f;
    for (int i = tid; i < cnt; i += 256) {
        unsigned u = plist[i];
        int row = (int)(u & 0x3FFFFu);
        int lbl = (int)(u >> 18);
        const float* xrow = cls_preds + (size_t)row * NUM_CLASSES;
        float cl = 0.f;
        #pragma unroll 5
        for (int c4 = 0; c4 < NUM_CLASSES / 4; ++c4) {
            float4 xv = reinterpret_cast<const float4*>(xrow)[c4];
            cl += focal_neg(xv.x);
            cl += focal_neg(xv.y);
            cl += focal_neg(xv.z);
            cl += focal_neg(xv.w);
        }
        cl += focal_target_corr(xrow[lbl]);
        cls_l += cl;
    }

    // reductions: wave shfl, then block via LDS
    #pragma unroll
    for (int off = 32; off > 0; off >>= 1) {
        box_l += __shfl_down(box_l, off);
        cls_l += __shfl_down(cls_l, off);
    }
    if (lane == 0) { redb[wave] = box_l; redc[wave] = cls_l; }
    __syncthreads();
    if (tid == 0) {
        float b0 = redb[0] + redb[1] + redb[2] + redb[3];
        float c0 = redc[0] + redc[1] + redc[2] + redc[3];
        atomicAdd(&acc[0], (double)b0);
        atomicAdd(&acc[1], (double)c0);
        atomicAdd(&acc[2], (double)cnt);
    }
}

__global__ void yolo_finalize(const double* __restrict__ acc, float* __restrict__ out) {
    if (threadIdx.x == 0) {
        double loss = (5.0 * acc[0] + acc[1]) / fmax(acc[2], 1.0);
        out[0] = (float)loss;
    }
}

extern "C" void kernel_launch(void* const* d_in, const int* in_sizes, int n_in,
                              void* d_out, int out_size, void* d_ws, size_t ws_size,
                              hipStream_t stream) {
    const float* box_preds = (const float*)d_in[0];
    const float* cls_preds = (const float*)d_in[1];
    const float* gt_boxes  = (const float*)d_in[2];
    const int*   gt_labels = (const int*)d_in[3];

    const int B = in_sizes[3] / M_GT;            // gt_labels is [B,M]
    const int N = in_sizes[0] / (4 * B);         // box_preds is [B,N,4]

    double* acc = (double*)d_ws;
    float*  out = (float*)d_out;

    yolo_init_acc<<<1, 64, 0, stream>>>(acc);

    dim3 grid((N + 255) / 256, B);
    yolo_fused_kernel<<<grid, 256, 0, stream>>>(box_preds, cls_preds, gt_boxes,
                                                gt_labels, acc, N);

    yolo_finalize<<<1, 64, 0, stream>>>(acc, out);
}